// Round 4
// baseline (335.970 us; speedup 1.0000x reference)
//
#include <hip/hip_runtime.h>

#define NB   256            // batch
#define NSQ  64             // squares used (rows 3..67)
#define NH   1024           // hidden
#define ND   256            // proj dim
#define NV   1858           // moves
#define M_   (NB * NSQ)     // 16384 GEMM rows
#define N_   512            // fp|tp concat
#define K_   1024
#define NKT  32             // K_/32 k-tiles

typedef __attribute__((ext_vector_type(4))) float f32x4;
typedef __attribute__((ext_vector_type(8))) short bf16x8;
typedef __attribute__((ext_vector_type(8))) unsigned short u16x8;

__device__ __forceinline__ unsigned short bf16_rne(float x) {
    unsigned u = __float_as_uint(x);
    unsigned r = u + 0x7fffu + ((u >> 16) & 1u);
    return (unsigned short)(r >> 16);
}

__device__ __forceinline__ void gload16(const void* g, void* l) {
    __builtin_amdgcn_global_load_lds(
        (const __attribute__((address_space(1))) unsigned int*)g,
        (__attribute__((address_space(3))) unsigned int*)l, 16, 0, 0);
}

// ---- cast into TILED-PERMUTED layout ----
// Global layout per buffer: [tile = rowblk128 * 32 + kt][8192 bytes]
// tile interior: [g=16-row group 0..7][s=k-chunk 0..3][r=row 0..15] * 16B
//   byte = g*1024 + s*256 + r*16 + e*2   (k = kt*32 + s*8 + e)
// => gemm staging is contiguous 8KB; frag read (kh,fr) at kh*256+fr*16 is
//    bank-conflict-free (8 distinct 16B positions per 8-lane phase).
__global__ __launch_bounds__(256) void cast_kernel(
    const float* __restrict__ hid,
    const float* __restrict__ Wf, const float* __restrict__ Wt,
    char* __restrict__ Ahi, char* __restrict__ Alo,
    char* __restrict__ Whi, char* __restrict__ Wlo) {
    int bid = blockIdx.x;
    int tid = threadIdx.x;
    int o = tid * 16;                 // byte offset in this block's 4KB run
    int g_l = o >> 10;                // 0..3
    int w = o & 1023;
    int s = w >> 8;                   // 0..3
    int r = (w >> 4) & 15;            // 0..15
    const float* src;
    char* dh; char* dl;
    if (bid < 8192) {                 // A: 256 rowblocks of 64 x 32 kt
        int brow = bid >> 5;          // 0..255 (64-row block)
        int kt = bid & 31;
        int m = brow * 64 + g_l * 16 + r;
        int b = m >> 6, sr = m & 63;
        int k = kt * 32 + s * 8;
        src = hid + (size_t)(b * 128 + 3 + sr) * NH + k;
        size_t outb = ((size_t)((brow >> 1) * 32 + kt) << 13) + ((brow & 1) << 12) + o;
        dh = Ahi + outb; dl = Alo + outb;
    } else {                          // W: 8 rowblocks of 64 x 32 kt
        int bid2 = bid - 8192;
        int nrb = bid2 >> 5;          // 0..7
        int kt = bid2 & 31;
        int n = nrb * 64 + g_l * 16 + r;
        int k = kt * 32 + s * 8;
        src = ((n < ND) ? (Wf + (size_t)n * NH) : (Wt + (size_t)(n - ND) * NH)) + k;
        size_t outb = ((size_t)((nrb >> 1) * 32 + kt) << 13) + ((nrb & 1) << 12) + o;
        dh = Whi + outb; dl = Wlo + outb;
    }
    float4 v0 = ((const float4*)src)[0];
    float4 v1 = ((const float4*)src)[1];
    float vv[8] = {v0.x, v0.y, v0.z, v0.w, v1.x, v1.y, v1.z, v1.w};
    u16x8 h, l;
#pragma unroll
    for (int j = 0; j < 8; ++j) {
        unsigned short hb = bf16_rne(vv[j]);
        float hf = __uint_as_float((unsigned)hb << 16);
        h[j] = hb;
        l[j] = bf16_rne(vv[j] - hf);
    }
    *(u16x8*)dh = h;
    *(u16x8*)dl = l;
}

// ---- gp[b][d] = hidden[b][0][:] . Wg[d][:] + bg[d], fp32 exact ----
__global__ __launch_bounds__(1024) void gp_kernel(
    const float* __restrict__ hid, const float* __restrict__ Wg,
    const float* __restrict__ bg, float* __restrict__ gp) {
    __shared__ float h[NH];
    int b = blockIdx.x;
    int tid = threadIdx.x;
    if (tid < 256) ((float4*)h)[tid] = ((const float4*)(hid + (size_t)b * 128 * NH))[tid];
    __syncthreads();
    int wave = tid >> 6, lane = tid & 63;
    const float4* hs = (const float4*)h;
    for (int dd = 0; dd < 16; ++dd) {
        int d = wave * 16 + dd;
        const float4* wrow = (const float4*)(Wg + (size_t)d * NH);
        float acc = 0.f;
#pragma unroll
        for (int p = 0; p < 4; ++p) {
            float4 w = wrow[p * 64 + lane];
            float4 x = hs[p * 64 + lane];
            acc += w.x * x.x + w.y * x.y + w.z * x.z + w.w * x.w;
        }
#pragma unroll
        for (int o = 32; o > 0; o >>= 1) acc += __shfl_xor(acc, o, 64);
        if (lane == 0) gp[(size_t)b * ND + d] = acc + bg[d];
    }
}

// ---- 3-term split-bf16 GEMM on pre-permuted tiles ----
// 128x128 tile, BK=32, 4 waves; linear contiguous staging; conflict-free
// fragment reads; XCD-chunked block swizzle (T1, 512%8==0 so bijective).
__global__ __launch_bounds__(256) void gemm3_kernel(
    const char* __restrict__ Ahi, const char* __restrict__ Alo,
    const char* __restrict__ Whi, const char* __restrict__ Wlo,
    const float* __restrict__ bfv, const float* __restrict__ btv,
    float* __restrict__ C) {
    __shared__ unsigned short lAh[128 * 32], lAl[128 * 32];
    __shared__ unsigned short lBh[128 * 32], lBl[128 * 32];
    int tid = threadIdx.x;
    int wgid = (blockIdx.x & 7) * 64 + (blockIdx.x >> 3);   // XCD-chunked
    int nt = wgid & 3;        // 4 n-tiles
    int mt = wgid >> 2;       // 128 m-tiles
    int lane = tid & 63, wv = tid >> 6;
    int wm = (wv >> 1) * 64, wn = (wv & 1) * 64;
    int fr = lane & 15, kh = lane >> 4;
    f32x4 acc[4][4] = {};

    for (int kt = 0; kt < NKT; ++kt) {
        size_t ta = (size_t)(mt * NKT + kt) << 13;
        size_t tb = (size_t)(nt * NKT + kt) << 13;
#pragma unroll
        for (int is = 0; is < 2; ++is) {
            int o = is * 4096 + tid * 16;
            gload16(Ahi + ta + o, (char*)lAh + o);
            gload16(Alo + ta + o, (char*)lAl + o);
            gload16(Whi + tb + o, (char*)lBh + o);
            gload16(Wlo + tb + o, (char*)lBl + o);
        }
        __syncthreads();
        bf16x8 ah[4], al[4], bh[4], bl[4];
#pragma unroll
        for (int f = 0; f < 4; ++f) {
            // permuted tile: group g=(row>>4), byte = g*1024 + kh*256 + fr*16
            int ea = (wm + f * 16) * 32 + kh * 128 + fr * 8;   // ushort idx
            int eb = (wn + f * 16) * 32 + kh * 128 + fr * 8;
            ah[f] = *(const bf16x8*)&lAh[ea];
            al[f] = *(const bf16x8*)&lAl[ea];
            bh[f] = *(const bf16x8*)&lBh[eb];
            bl[f] = *(const bf16x8*)&lBl[eb];
        }
#pragma unroll
        for (int i = 0; i < 4; ++i)
#pragma unroll
            for (int j = 0; j < 4; ++j) {
                acc[i][j] = __builtin_amdgcn_mfma_f32_16x16x32_bf16(ah[i], bh[j], acc[i][j], 0, 0, 0);
                acc[i][j] = __builtin_amdgcn_mfma_f32_16x16x32_bf16(ah[i], bl[j], acc[i][j], 0, 0, 0);
                acc[i][j] = __builtin_amdgcn_mfma_f32_16x16x32_bf16(al[i], bh[j], acc[i][j], 0, 0, 0);
            }
        __syncthreads();
    }

    const float* bias = (nt < 2) ? bfv : btv;
    int nb0 = nt * 128 - ((nt < 2) ? 0 : 256);
#pragma unroll
    for (int j = 0; j < 4; ++j) {
        int ncol = nt * 128 + wn + j * 16 + fr;
        float bv = bias[nb0 + wn + j * 16 + fr];
#pragma unroll
        for (int i = 0; i < 4; ++i) {
            int mrow = mt * 128 + wm + i * 16 + kh * 4;
#pragma unroll
            for (int r = 0; r < 4; ++r) {
                C[(size_t)(mrow + r) * N_ + ncol] = acc[i][j][r] + bv;
            }
        }
    }
}

// ---- gather + relu-dot: out[b][v] ----
__global__ __launch_bounds__(1024) void out_kernel(
    const float* __restrict__ C, const float* __restrict__ gp,
    const float* __restrict__ promo_tab, const float* __restrict__ Wsv,
    const float* __restrict__ bsv,
    const int* __restrict__ from_sqs, const int* __restrict__ to_sqs,
    const int* __restrict__ ptypes, float* __restrict__ out) {
    __shared__ float cb[NSQ * N_];       // 128 KB: fp|tp rows of this b
    __shared__ float gpl[ND];
    __shared__ float wsl[ND];
    __shared__ float pl[5 * ND];
    __shared__ int fsq[NV], tsq[NV], pty[NV];
    int b = blockIdx.x;
    int tid = threadIdx.x;
    const float4* src = (const float4*)(C + (size_t)b * NSQ * N_);
    float4* dst = (float4*)cb;
#pragma unroll
    for (int i = 0; i < 8; ++i) dst[tid + i * 1024] = src[tid + i * 1024];
    if (tid < 64) ((float4*)gpl)[tid] = ((const float4*)(gp + (size_t)b * ND))[tid];
    else if (tid < 128) ((float4*)wsl)[tid - 64] = ((const float4*)Wsv)[tid - 64];
    else if (tid < 448) ((float4*)pl)[tid - 128] = ((const float4*)promo_tab)[tid - 128];
    for (int v = tid; v < NV; v += 1024) {
        fsq[v] = from_sqs[v];
        tsq[v] = to_sqs[v];
        pty[v] = ptypes[v];
    }
    __syncthreads();

    int wave = tid >> 6, lane = tid & 63;
    float bias0 = bsv[0];
    const float4* cb4 = (const float4*)cb;
    const float4* gp4 = (const float4*)gpl;
    const float4* ws4 = (const float4*)wsl;
    const float4* pl4 = (const float4*)pl;
    for (int v = wave; v < NV; v += 16) {
        int sf = fsq[v];
        int st = tsq[v];
        int p  = pty[v];
        float4 a = cb4[sf * 128 + lane];           // fp cols 0..255
        float4 t = cb4[st * 128 + 64 + lane];      // tp cols 256..511
        float4 g = gp4[lane];
        float4 pp = pl4[p * 64 + lane];
        float4 w = ws4[lane];
        float c0 = a.x * t.x + g.x + pp.x;
        float c1 = a.y * t.y + g.y + pp.y;
        float c2 = a.z * t.z + g.z + pp.z;
        float c3 = a.w * t.w + g.w + pp.w;
        float s = fmaxf(c0, 0.f) * w.x + fmaxf(c1, 0.f) * w.y +
                  fmaxf(c2, 0.f) * w.z + fmaxf(c3, 0.f) * w.w;
#pragma unroll
        for (int o = 32; o > 0; o >>= 1) s += __shfl_xor(s, o, 64);
        if (lane == 0) out[(size_t)b * NV + v] = s + bias0;
    }
}

extern "C" void kernel_launch(void* const* d_in, const int* in_sizes, int n_in,
                              void* d_out, int out_size, void* d_ws, size_t ws_size,
                              hipStream_t stream) {
    (void)in_sizes; (void)n_in; (void)out_size; (void)ws_size;
    const float* hid   = (const float*)d_in[0];
    const float* Wf    = (const float*)d_in[1];
    const float* bfv   = (const float*)d_in[2];
    const float* Wt    = (const float*)d_in[3];
    const float* btv   = (const float*)d_in[4];
    const float* Wg    = (const float*)d_in[5];
    const float* bgv   = (const float*)d_in[6];
    const float* promo = (const float*)d_in[7];
    const float* Wsv   = (const float*)d_in[8];
    const float* bsv   = (const float*)d_in[9];
    const int* from_sqs = (const int*)d_in[10];
    const int* to_sqs   = (const int*)d_in[11];
    const int* ptypes   = (const int*)d_in[12];
    float* out = (float*)d_out;

    char* ws = (char*)d_ws;
    // layout: Ahi 32MiB | Alo 32MiB | Whi 1MiB | Wlo 1MiB | C 32MiB | gp 256KiB
    char* Ahi = ws;
    char* Alo = ws + 33554432;
    char* Whi = ws + 67108864;
    char* Wlo = ws + 68157440;
    float* C  = (float*)(ws + 69206016);
    float* gp = (float*)(ws + 102760448);

    cast_kernel<<<8448, 256, 0, stream>>>(hid, Wf, Wt, Ahi, Alo, Whi, Wlo);
    gp_kernel<<<256, 1024, 0, stream>>>(hid, Wg, bgv, gp);
    gemm3_kernel<<<512, 256, 0, stream>>>(Ahi, Alo, Whi, Wlo, bfv, btv, C);
    out_kernel<<<256, 1024, 0, stream>>>(C, gp, promo, Wsv, bsv,
                                         from_sqs, to_sqs, ptypes, out);
}

// Round 6
// 334.351 us; speedup vs baseline: 1.0048x; 1.0048x over previous
//
#include <hip/hip_runtime.h>

#define NB   256            // batch
#define NSQ  64             // squares used (rows 3..67)
#define NH   1024           // hidden
#define ND   256            // proj dim
#define NV   1858           // moves
#define M_   (NB * NSQ)     // 16384 GEMM rows
#define N_   512            // fp|tp concat
#define K_   1024
#define NKT  32             // K_/32 k-tiles
#define BUFB 49152          // 48 KB per pipeline buffer

typedef __attribute__((ext_vector_type(4))) float f32x4;
typedef __attribute__((ext_vector_type(8))) short bf16x8;
typedef __attribute__((ext_vector_type(8))) unsigned short u16x8;

__device__ __forceinline__ unsigned short bf16_rne(float x) {
    unsigned u = __float_as_uint(x);
    unsigned r = u + 0x7fffu + ((u >> 16) & 1u);
    return (unsigned short)(r >> 16);
}

__device__ __forceinline__ void gload16(const void* g, void* l) {
    __builtin_amdgcn_global_load_lds(
        (const __attribute__((address_space(1))) unsigned int*)g,
        (__attribute__((address_space(3))) unsigned int*)l, 16, 0, 0);
}

// ---- cast into TILED-PERMUTED layout (unchanged from R4) ----
// Global layout per buffer: [tile = rowblk128 * 32 + kt][8192 bytes]
// tile interior: [g=16-row group 0..7][s=k-chunk 0..3][r=row 0..15] * 16B
__global__ __launch_bounds__(256) void cast_kernel(
    const float* __restrict__ hid,
    const float* __restrict__ Wf, const float* __restrict__ Wt,
    char* __restrict__ Ahi, char* __restrict__ Alo,
    char* __restrict__ Whi, char* __restrict__ Wlo) {
    int bid = blockIdx.x;
    int tid = threadIdx.x;
    int o = tid * 16;
    int g_l = o >> 10;
    int w = o & 1023;
    int s = w >> 8;
    int r = (w >> 4) & 15;
    const float* src;
    char* dh; char* dl;
    if (bid < 8192) {                 // A: 256 rowblocks of 64 x 32 kt
        int brow = bid >> 5;
        int kt = bid & 31;
        int m = brow * 64 + g_l * 16 + r;
        int b = m >> 6, sr = m & 63;
        int k = kt * 32 + s * 8;
        src = hid + (size_t)(b * 128 + 3 + sr) * NH + k;
        size_t outb = ((size_t)((brow >> 1) * 32 + kt) << 13) + ((brow & 1) << 12) + o;
        dh = Ahi + outb; dl = Alo + outb;
    } else {                          // W: 8 rowblocks of 64 x 32 kt
        int bid2 = bid - 8192;
        int nrb = bid2 >> 5;
        int kt = bid2 & 31;
        int n = nrb * 64 + g_l * 16 + r;
        int k = kt * 32 + s * 8;
        src = ((n < ND) ? (Wf + (size_t)n * NH) : (Wt + (size_t)(n - ND) * NH)) + k;
        size_t outb = ((size_t)((nrb >> 1) * 32 + kt) << 13) + ((nrb & 1) << 12) + o;
        dh = Whi + outb; dl = Wlo + outb;
    }
    float4 v0 = ((const float4*)src)[0];
    float4 v1 = ((const float4*)src)[1];
    float vv[8] = {v0.x, v0.y, v0.z, v0.w, v1.x, v1.y, v1.z, v1.w};
    u16x8 h, l;
#pragma unroll
    for (int j = 0; j < 8; ++j) {
        unsigned short hb = bf16_rne(vv[j]);
        float hf = __uint_as_float((unsigned)hb << 16);
        h[j] = hb;
        l[j] = bf16_rne(vv[j] - hf);
    }
    *(u16x8*)dh = h;
    *(u16x8*)dl = l;
}

// ---- gp[b][d] = hidden[b][0][:] . Wg[d][:] + bg[d], fp32 exact ----
__global__ __launch_bounds__(1024) void gp_kernel(
    const float* __restrict__ hid, const float* __restrict__ Wg,
    const float* __restrict__ bg, float* __restrict__ gp) {
    __shared__ float h[NH];
    int b = blockIdx.x;
    int tid = threadIdx.x;
    if (tid < 256) ((float4*)h)[tid] = ((const float4*)(hid + (size_t)b * 128 * NH))[tid];
    __syncthreads();
    int wave = tid >> 6, lane = tid & 63;
    const float4* hs = (const float4*)h;
    for (int dd = 0; dd < 16; ++dd) {
        int d = wave * 16 + dd;
        const float4* wrow = (const float4*)(Wg + (size_t)d * NH);
        float acc = 0.f;
#pragma unroll
        for (int p = 0; p < 4; ++p) {
            float4 w = wrow[p * 64 + lane];
            float4 x = hs[p * 64 + lane];
            acc += w.x * x.x + w.y * x.y + w.z * x.z + w.w * x.w;
        }
#pragma unroll
        for (int o = 32; o > 0; o >>= 1) acc += __shfl_xor(acc, o, 64);
        if (lane == 0) gp[(size_t)b * ND + d] = acc + bg[d];
    }
}

// ---- 3-term split-bf16 GEMM, 8-phase-class schedule (T3+T4+T5) ----
// BM=256, BN=128, BK=32, 8 waves (4M x 2N), 3-deep LDS pipeline (144 KB),
// counted vmcnt(6) once per K-step, raw s_barrier (no compiler drain).
__global__ __launch_bounds__(512) void gemm3_kernel(
    const char* __restrict__ Ahi, const char* __restrict__ Alo,
    const char* __restrict__ Whi, const char* __restrict__ Wlo,
    const float* __restrict__ bfv, const float* __restrict__ btv,
    float* __restrict__ C) {
    __shared__ char lds[3 * BUFB];    // 144 KB: 3 x [Ahi16K|Alo16K|Bhi8K|Blo8K]
    int tid = threadIdx.x;
    int lane = tid & 63, wv = tid >> 6;          // 8 waves
    int wgid = (blockIdx.x & 7) * 32 + (blockIdx.x >> 3);   // XCD-chunked (256%8==0)
    int nt = wgid & 3;        // 4 n-tiles of 128
    int mt = wgid >> 2;       // 64 m-tiles of 256
    int wm = wv >> 1;         // 0..3: 64-row strip
    int wnw = wv & 1;         // 0..1: 64-col strip
    int fr = lane & 15, kh = lane >> 4;

    // --- precompute this thread's 6 stage segments (1 KB each per wave) ---
    // seg = wv*6 + l; regions: [0,8)=Ahi tile(2mt), [8,16)=Ahi tile(2mt+1),
    // [16,24)=Alo t0, [24,32)=Alo t1, [32,40)=Bhi, [40,48)=Blo.
    const char* gsrc[6];
    int loff[6];
#pragma unroll
    for (int l = 0; l < 6; ++l) {
        int seg = wv * 6 + l;
        const char* base; int lo;
        if (seg < 8)       { base = Ahi + ((size_t)((2*mt)*NKT) << 13)   + seg*1024;      lo = seg*1024; }
        else if (seg < 16) { base = Ahi + ((size_t)((2*mt+1)*NKT) << 13) + (seg-8)*1024;  lo = 8192  + (seg-8)*1024; }
        else if (seg < 24) { base = Alo + ((size_t)((2*mt)*NKT) << 13)   + (seg-16)*1024; lo = 16384 + (seg-16)*1024; }
        else if (seg < 32) { base = Alo + ((size_t)((2*mt+1)*NKT) << 13) + (seg-24)*1024; lo = 24576 + (seg-24)*1024; }
        else if (seg < 40) { base = Whi + ((size_t)(nt*NKT) << 13)       + (seg-32)*1024; lo = 32768 + (seg-32)*1024; }
        else               { base = Wlo + ((size_t)(nt*NKT) << 13)       + (seg-40)*1024; lo = 40960 + (seg-40)*1024; }
        gsrc[l] = base + lane * 16;
        loff[l] = lo + lane * 16;
    }

#define STG(l, ktn, sb) gload16(gsrc[l] + ((size_t)(ktn) << 13), lds + (sb) * BUFB + loff[l])

    f32x4 acc[4][4] = {};

    // --- prologue: stage k-steps 0 and 1; wait step 0; barrier ---
#pragma unroll
    for (int l = 0; l < 6; ++l) STG(l, 0, 0);
#pragma unroll
    for (int l = 0; l < 6; ++l) STG(l, 1, 1);
    asm volatile("s_waitcnt vmcnt(6)" ::: "memory");
    __builtin_amdgcn_s_barrier();
    __builtin_amdgcn_sched_barrier(0);

    int rcur = 0, snext = 2;         // read buf t%3, stage buf (t+2)%3
    int aoff0 = (wm >> 1) * 8192 + (wm & 1) * 4096 + kh * 256 + fr * 16;
    int boff0 = 32768 + wnw * 4096 + kh * 256 + fr * 16;

#pragma unroll 1
    for (int t = 0; t < NKT; ++t) {
        const char* cb = lds + rcur * BUFB;
        int ktn = (t + 2) & (NKT - 1);          // wrap: dummy re-stage at t>=30
        bf16x8 bh[4], bl[4];

        // ---- phase 0: all B frags + A frag 0; stage segs 0,1 ----
#pragma unroll
        for (int j = 0; j < 4; ++j) {
            bh[j] = *(const bf16x8*)(cb + boff0 + j * 1024);
            bl[j] = *(const bf16x8*)(cb + boff0 + 8192 + j * 1024);
        }
        bf16x8 ah0 = *(const bf16x8*)(cb + aoff0);
        bf16x8 al0 = *(const bf16x8*)(cb + 16384 + aoff0);
        STG(0, ktn, snext); STG(1, ktn, snext);
        __builtin_amdgcn_s_barrier();
        __builtin_amdgcn_s_setprio(1);
#pragma unroll
        for (int j = 0; j < 4; ++j) {
            acc[0][j] = __builtin_amdgcn_mfma_f32_16x16x32_bf16(ah0, bh[j], acc[0][j], 0, 0, 0);
            acc[0][j] = __builtin_amdgcn_mfma_f32_16x16x32_bf16(ah0, bl[j], acc[0][j], 0, 0, 0);
            acc[0][j] = __builtin_amdgcn_mfma_f32_16x16x32_bf16(al0, bh[j], acc[0][j], 0, 0, 0);
        }
        __builtin_amdgcn_s_setprio(0);
        __builtin_amdgcn_s_barrier();
        __builtin_amdgcn_sched_barrier(0);

        // ---- phase 1: A frag 1; stage segs 2,3 ----
        bf16x8 ah1 = *(const bf16x8*)(cb + aoff0 + 1024);
        bf16x8 al1 = *(const bf16x8*)(cb + 16384 + aoff0 + 1024);
        STG(2, ktn, snext); STG(3, ktn, snext);
        __builtin_amdgcn_s_barrier();
        __builtin_amdgcn_s_setprio(1);
#pragma unroll
        for (int j = 0; j < 4; ++j) {
            acc[1][j] = __builtin_amdgcn_mfma_f32_16x16x32_bf16(ah1, bh[j], acc[1][j], 0, 0, 0);
            acc[1][j] = __builtin_amdgcn_mfma_f32_16x16x32_bf16(ah1, bl[j], acc[1][j], 0, 0, 0);
            acc[1][j] = __builtin_amdgcn_mfma_f32_16x16x32_bf16(al1, bh[j], acc[1][j], 0, 0, 0);
        }
        __builtin_amdgcn_s_setprio(0);
        __builtin_amdgcn_s_barrier();
        __builtin_amdgcn_sched_barrier(0);

        // ---- phase 2: A frag 2; stage seg 4 ----
        bf16x8 ah2 = *(const bf16x8*)(cb + aoff0 + 2048);
        bf16x8 al2 = *(const bf16x8*)(cb + 16384 + aoff0 + 2048);
        STG(4, ktn, snext);
        __builtin_amdgcn_s_barrier();
        __builtin_amdgcn_s_setprio(1);
#pragma unroll
        for (int j = 0; j < 4; ++j) {
            acc[2][j] = __builtin_amdgcn_mfma_f32_16x16x32_bf16(ah2, bh[j], acc[2][j], 0, 0, 0);
            acc[2][j] = __builtin_amdgcn_mfma_f32_16x16x32_bf16(ah2, bl[j], acc[2][j], 0, 0, 0);
            acc[2][j] = __builtin_amdgcn_mfma_f32_16x16x32_bf16(al2, bh[j], acc[2][j], 0, 0, 0);
        }
        __builtin_amdgcn_s_setprio(0);
        __builtin_amdgcn_s_barrier();
        __builtin_amdgcn_sched_barrier(0);

        // ---- phase 3: A frag 3; stage seg 5; counted vmcnt(6) ----
        bf16x8 ah3 = *(const bf16x8*)(cb + aoff0 + 3072);
        bf16x8 al3 = *(const bf16x8*)(cb + 16384 + aoff0 + 3072);
        STG(5, ktn, snext);
        __builtin_amdgcn_s_barrier();
        __builtin_amdgcn_s_setprio(1);
#pragma unroll
        for (int j = 0; j < 4; ++j) {
            acc[3][j] = __builtin_amdgcn_mfma_f32_16x16x32_bf16(ah3, bh[j], acc[3][j], 0, 0, 0);
            acc[3][j] = __builtin_amdgcn_mfma_f32_16x16x32_bf16(ah3, bl[j], acc[3][j], 0, 0, 0);
            acc[3][j] = __builtin_amdgcn_mfma_f32_16x16x32_bf16(al3, bh[j], acc[3][j], 0, 0, 0);
        }
        __builtin_amdgcn_s_setprio(0);
        // next step's buffer (staged 1 step ago) must be complete: 12 in
        // flight (t+1:6, t+2:6) -> wait 6 retires exactly t+1's loads.
        asm volatile("s_waitcnt vmcnt(6)" ::: "memory");
        __builtin_amdgcn_s_barrier();
        __builtin_amdgcn_sched_barrier(0);

        rcur = (rcur == 2) ? 0 : rcur + 1;
        snext = (snext == 2) ? 0 : snext + 1;
    }

    // ---- epilogue: bias + C write ----
    const float* bias = (nt < 2) ? bfv : btv;
    int nb0 = nt * 128 - ((nt < 2) ? 0 : 256);
#pragma unroll
    for (int j = 0; j < 4; ++j) {
        int nc = wnw * 64 + j * 16 + fr;
        int ncol = nt * 128 + nc;
        float bv = bias[nb0 + nc];
#pragma unroll
        for (int i = 0; i < 4; ++i) {
            int mrow = mt * 256 + wm * 64 + i * 16 + kh * 4;
#pragma unroll
            for (int r = 0; r < 4; ++r) {
                C[(size_t)(mrow + r) * N_ + ncol] = acc[i][j][r] + bv;
            }
        }
    }
#undef STG
}

// ---- gather + relu-dot: out[b][v] ----
__global__ __launch_bounds__(1024) void out_kernel(
    const float* __restrict__ C, const float* __restrict__ gp,
    const float* __restrict__ promo_tab, const float* __restrict__ Wsv,
    const float* __restrict__ bsv,
    const int* __restrict__ from_sqs, const int* __restrict__ to_sqs,
    const int* __restrict__ ptypes, float* __restrict__ out) {
    __shared__ float cb[NSQ * N_];       // 128 KB: fp|tp rows of this b
    __shared__ float gpl[ND];
    __shared__ float wsl[ND];
    __shared__ float pl[5 * ND];
    __shared__ int fsq[NV], tsq[NV], pty[NV];
    int b = blockIdx.x;
    int tid = threadIdx.x;
    const float4* src = (const float4*)(C + (size_t)b * NSQ * N_);
    float4* dst = (float4*)cb;
#pragma unroll
    for (int i = 0; i < 8; ++i) dst[tid + i * 1024] = src[tid + i * 1024];
    if (tid < 64) ((float4*)gpl)[tid] = ((const float4*)(gp + (size_t)b * ND))[tid];
    else if (tid < 128) ((float4*)wsl)[tid - 64] = ((const float4*)Wsv)[tid - 64];
    else if (tid < 448) ((float4*)pl)[tid - 128] = ((const float4*)promo_tab)[tid - 128];
    for (int v = tid; v < NV; v += 1024) {
        fsq[v] = from_sqs[v];
        tsq[v] = to_sqs[v];
        pty[v] = ptypes[v];
    }
    __syncthreads();

    int wave = tid >> 6, lane = tid & 63;
    float bias0 = bsv[0];
    const float4* cb4 = (const float4*)cb;
    const float4* gp4 = (const float4*)gpl;
    const float4* ws4 = (const float4*)wsl;
    const float4* pl4 = (const float4*)pl;
    for (int v = wave; v < NV; v += 16) {
        int sf = fsq[v];
        int st = tsq[v];
        int p  = pty[v];
        float4 a = cb4[sf * 128 + lane];
        float4 t = cb4[st * 128 + 64 + lane];
        float4 g = gp4[lane];
        float4 pp = pl4[p * 64 + lane];
        float4 w = ws4[lane];
        float c0 = a.x * t.x + g.x + pp.x;
        float c1 = a.y * t.y + g.y + pp.y;
        float c2 = a.z * t.z + g.z + pp.z;
        float c3 = a.w * t.w + g.w + pp.w;
        float s = fmaxf(c0, 0.f) * w.x + fmaxf(c1, 0.f) * w.y +
                  fmaxf(c2, 0.f) * w.z + fmaxf(c3, 0.f) * w.w;
#pragma unroll
        for (int o = 32; o > 0; o >>= 1) s += __shfl_xor(s, o, 64);
        if (lane == 0) out[(size_t)b * NV + v] = s + bias0;
    }
}

extern "C" void kernel_launch(void* const* d_in, const int* in_sizes, int n_in,
                              void* d_out, int out_size, void* d_ws, size_t ws_size,
                              hipStream_t stream) {
    (void)in_sizes; (void)n_in; (void)out_size; (void)ws_size;
    const float* hid   = (const float*)d_in[0];
    const float* Wf    = (const float*)d_in[1];
    const float* bfv   = (const float*)d_in[2];
    const float* Wt    = (const float*)d_in[3];
    const float* btv   = (const float*)d_in[4];
    const float* Wg    = (const float*)d_in[5];
    const float* bgv   = (const float*)d_in[6];
    const float* promo = (const float*)d_in[7];
    const float* Wsv   = (const float*)d_in[8];
    const float* bsv   = (const float*)d_in[9];
    const int* from_sqs = (const int*)d_in[10];
    const int* to_sqs   = (const int*)d_in[11];
    const int* ptypes   = (const int*)d_in[12];
    float* out = (float*)d_out;

    char* ws = (char*)d_ws;
    // layout: Ahi 32MiB | Alo 32MiB | Whi 1MiB | Wlo 1MiB | C 32MiB | gp 256KiB
    char* Ahi = ws;
    char* Alo = ws + 33554432;
    char* Whi = ws + 67108864;
    char* Wlo = ws + 68157440;
    float* C  = (float*)(ws + 69206016);
    float* gp = (float*)(ws + 102760448);

    cast_kernel<<<8448, 256, 0, stream>>>(hid, Wf, Wt, Ahi, Alo, Whi, Wlo);
    gp_kernel<<<256, 1024, 0, stream>>>(hid, Wg, bgv, gp);
    gemm3_kernel<<<256, 512, 0, stream>>>(Ahi, Alo, Whi, Wlo, bfv, btv, C);
    out_kernel<<<256, 1024, 0, stream>>>(C, gp, promo, Wsv, bsv,
                                         from_sqs, to_sqs, ptypes, out);
}